// Round 1
// baseline (115.165 us; speedup 1.0000x reference)
//
#include <hip/hip_runtime.h>

// PointPillarScatter: grid 432x496, 64 channels, B=8 (derived from out_size)
#define PNX 432
#define PNY 496
#define PC  64

// ---------- main path: inverse-map gather ----------

// Fill cell->pillar map with -1 (int4 stores; n4 = ncell/4, ncell % 4 == 0)
__global__ __launch_bounds__(256) void pps_fill_neg1(int4* __restrict__ map4, int n4) {
    int i = blockIdx.x * blockDim.x + threadIdx.x;
    if (i < n4) map4[i] = make_int4(-1, -1, -1, -1);
}

// One thread per pillar: map[b*NY*NX + z + y*NX + x] = p  (cells are unique)
__global__ __launch_bounds__(256) void pps_scatter_idx(const int* __restrict__ coords,
                                                       int* __restrict__ map, int P) {
    int p = blockIdx.x * blockDim.x + threadIdx.x;
    if (p >= P) return;
    int b = coords[p * 4 + 0];
    int z = coords[p * 4 + 1];
    int y = coords[p * 4 + 2];
    int x = coords[p * 4 + 3];
    map[(size_t)b * (PNY * PNX) + z + y * PNX + x] = p;
}

// One thread per 4 consecutive cells; writes all 64 channels as float4 per plane.
// NY*NX = 214272 is divisible by 4 -> a thread's 4 cells never cross a batch.
__global__ __launch_bounds__(256) void pps_gather(const float* __restrict__ feat,
                                                  const int* __restrict__ map,
                                                  float* __restrict__ out, int ncell4) {
    int t = blockIdx.x * blockDim.x + threadIdx.x;
    if (t >= ncell4) return;
    int cell0 = t << 2;
    int b   = cell0 / (PNY * PNX);
    int loc = cell0 - b * (PNY * PNX);
    int4 pp = *reinterpret_cast<const int4*>(map + cell0);
    const size_t plane = (size_t)PNY * PNX;
    float* obase = out + (size_t)b * PC * plane + loc;
    const float4 z4 = make_float4(0.f, 0.f, 0.f, 0.f);
#pragma unroll
    for (int c = 0; c < PC; c += 4) {
        float4 f0 = (pp.x >= 0) ? *reinterpret_cast<const float4*>(feat + (size_t)pp.x * PC + c) : z4;
        float4 f1 = (pp.y >= 0) ? *reinterpret_cast<const float4*>(feat + (size_t)pp.y * PC + c) : z4;
        float4 f2 = (pp.z >= 0) ? *reinterpret_cast<const float4*>(feat + (size_t)pp.z * PC + c) : z4;
        float4 f3 = (pp.w >= 0) ? *reinterpret_cast<const float4*>(feat + (size_t)pp.w * PC + c) : z4;
        *reinterpret_cast<float4*>(obase + (size_t)(c + 0) * plane) = make_float4(f0.x, f1.x, f2.x, f3.x);
        *reinterpret_cast<float4*>(obase + (size_t)(c + 1) * plane) = make_float4(f0.y, f1.y, f2.y, f3.y);
        *reinterpret_cast<float4*>(obase + (size_t)(c + 2) * plane) = make_float4(f0.z, f1.z, f2.z, f3.z);
        *reinterpret_cast<float4*>(obase + (size_t)(c + 3) * plane) = make_float4(f0.w, f1.w, f2.w, f3.w);
    }
}

// ---------- fallback path (ws too small): zero + direct scatter ----------

__global__ __launch_bounds__(256) void pps_zero(float4* __restrict__ out4, int n4) {
    int i = blockIdx.x * blockDim.x + threadIdx.x;
    if (i < n4) out4[i] = make_float4(0.f, 0.f, 0.f, 0.f);
}

__global__ __launch_bounds__(256) void pps_scatter_feat(const float* __restrict__ feat,
                                                        const int* __restrict__ coords,
                                                        float* __restrict__ out, int total) {
    int g = blockIdx.x * blockDim.x + threadIdx.x;
    if (g >= total) return;
    int p = g >> 6;      // pillar
    int c = g & 63;      // channel
    int b = coords[p * 4 + 0];
    int z = coords[p * 4 + 1];
    int y = coords[p * 4 + 2];
    int x = coords[p * 4 + 3];
    const size_t plane = (size_t)PNY * PNX;
    out[((size_t)b * PC + c) * plane + z + y * PNX + x] = feat[g];
}

extern "C" void kernel_launch(void* const* d_in, const int* in_sizes, int n_in,
                              void* d_out, int out_size, void* d_ws, size_t ws_size,
                              hipStream_t stream) {
    const float* feat   = (const float*)d_in[0];
    const int*   coords = (const int*)d_in[1];
    float* out = (float*)d_out;

    const int P = in_sizes[1] / 4;                   // coords is [P,4]
    const int B = out_size / (PC * PNY * PNX);       // derive batch from out_size
    const size_t ncell = (size_t)B * PNY * PNX;      // divisible by 4
    const size_t need  = ncell * sizeof(int);

    if (ws_size >= need) {
        int* map = (int*)d_ws;
        int n4 = (int)(ncell / 4);
        pps_fill_neg1<<<(n4 + 255) / 256, 256, 0, stream>>>((int4*)map, n4);
        pps_scatter_idx<<<(P + 255) / 256, 256, 0, stream>>>(coords, map, P);
        pps_gather<<<(n4 + 255) / 256, 256, 0, stream>>>(feat, map, out, n4);
    } else {
        int n4 = out_size / 4;
        pps_zero<<<(n4 + 255) / 256, 256, 0, stream>>>((float4*)out, n4);
        int total = P * PC;
        pps_scatter_feat<<<(total + 255) / 256, 256, 0, stream>>>(feat, coords, out, total);
    }
}

// Round 2
// 94.586 us; speedup vs baseline: 1.2176x; 1.2176x over previous
//
#include <hip/hip_runtime.h>

// PointPillarScatter: KITTI grid 432x496, 64 channels, B derived from out_size
#define PNX 432
#define PNY 496
#define PC  64

typedef float f32x4 __attribute__((ext_vector_type(4)));

// One thread per pillar: map[b*NY*NX + z + y*NX + x] = p (cells unique).
// Block 0 also zeroes the 64-float zero-row used by the gather.
__global__ __launch_bounds__(256) void pps_scatter_idx(const int* __restrict__ coords,
                                                       int* __restrict__ map,
                                                       float* __restrict__ zrow, int P) {
    int p = blockIdx.x * blockDim.x + threadIdx.x;
    if (blockIdx.x == 0 && threadIdx.x < PC) zrow[threadIdx.x] = 0.f;
    if (p >= P) return;
    int b = coords[p * 4 + 0];
    int z = coords[p * 4 + 1];
    int y = coords[p * 4 + 2];
    int x = coords[p * 4 + 3];
    map[(size_t)b * (PNY * PNX) + z + y * PNX + x] = p;
}

// One thread per 4 consecutive cells. Empty cells read the L1-hot zero-row so
// every load is unconditional. Loads are batched 16-wide (4 rows x 4 float4)
// before the 16 transposed nontemporal stores, forcing in-flight MLP.
__global__ __launch_bounds__(256) void pps_gather(const float* __restrict__ feat,
                                                  const int* __restrict__ map,
                                                  const float* __restrict__ zrow,
                                                  float* __restrict__ out, int ncell4) {
    int t = blockIdx.x * blockDim.x + threadIdx.x;
    if (t >= ncell4) return;
    int cell0 = t << 2;
    int b   = cell0 / (PNY * PNX);       // 4-cell groups never cross a batch (NY*NX % 4 == 0)
    int loc = cell0 - b * (PNY * PNX);
    int4 pp = *reinterpret_cast<const int4*>(map + cell0);
    const float* r0 = (pp.x >= 0) ? feat + (size_t)pp.x * PC : zrow;
    const float* r1 = (pp.y >= 0) ? feat + (size_t)pp.y * PC : zrow;
    const float* r2 = (pp.z >= 0) ? feat + (size_t)pp.z * PC : zrow;
    const float* r3 = (pp.w >= 0) ? feat + (size_t)pp.w * PC : zrow;
    const size_t plane = (size_t)PNY * PNX;
    float* obase = out + (size_t)b * PC * plane + loc;
#pragma unroll
    for (int cc = 0; cc < PC; cc += 16) {
        f32x4 f0[4], f1[4], f2[4], f3[4];
#pragma unroll
        for (int j = 0; j < 4; ++j) {
            f0[j] = *reinterpret_cast<const f32x4*>(r0 + cc + j * 4);
            f1[j] = *reinterpret_cast<const f32x4*>(r1 + cc + j * 4);
            f2[j] = *reinterpret_cast<const f32x4*>(r2 + cc + j * 4);
            f3[j] = *reinterpret_cast<const f32x4*>(r3 + cc + j * 4);
        }
#pragma unroll
        for (int j = 0; j < 4; ++j) {
#pragma unroll
            for (int k = 0; k < 4; ++k) {
                f32x4 v = { f0[j][k], f1[j][k], f2[j][k], f3[j][k] };
                __builtin_nontemporal_store(
                    v, reinterpret_cast<f32x4*>(obase + (size_t)(cc + j * 4 + k) * plane));
            }
        }
    }
}

// ---------- fallback path (ws too small): zero + direct scatter ----------

__global__ __launch_bounds__(256) void pps_zero(float4* __restrict__ out4, int n4) {
    int i = blockIdx.x * blockDim.x + threadIdx.x;
    if (i < n4) out4[i] = make_float4(0.f, 0.f, 0.f, 0.f);
}

__global__ __launch_bounds__(256) void pps_scatter_feat(const float* __restrict__ feat,
                                                        const int* __restrict__ coords,
                                                        float* __restrict__ out, int total) {
    int g = blockIdx.x * blockDim.x + threadIdx.x;
    if (g >= total) return;
    int p = g >> 6;      // pillar
    int c = g & 63;      // channel
    int b = coords[p * 4 + 0];
    int z = coords[p * 4 + 1];
    int y = coords[p * 4 + 2];
    int x = coords[p * 4 + 3];
    const size_t plane = (size_t)PNY * PNX;
    out[((size_t)b * PC + c) * plane + z + y * PNX + x] = feat[g];
}

extern "C" void kernel_launch(void* const* d_in, const int* in_sizes, int n_in,
                              void* d_out, int out_size, void* d_ws, size_t ws_size,
                              hipStream_t stream) {
    const float* feat   = (const float*)d_in[0];
    const int*   coords = (const int*)d_in[1];
    float* out = (float*)d_out;

    const int P = in_sizes[1] / 4;                   // coords is [P,4]
    const int B = out_size / (PC * PNY * PNX);       // derive batch from out_size
    const size_t ncell = (size_t)B * PNY * PNX;      // divisible by 4
    const size_t mapbytes = ncell * sizeof(int);
    const size_t zoff = (mapbytes + 255) & ~(size_t)255;
    const size_t need = zoff + PC * sizeof(float);

    if (ws_size >= need) {
        int*   map  = (int*)d_ws;
        float* zrow = (float*)((char*)d_ws + zoff);
        // 0xFF bytes == int32 -1 : empty-cell marker
        hipMemsetAsync(map, 0xFF, mapbytes, stream);
        pps_scatter_idx<<<(P + 255) / 256, 256, 0, stream>>>(coords, map, zrow, P);
        int n4 = (int)(ncell / 4);
        pps_gather<<<(n4 + 255) / 256, 256, 0, stream>>>(feat, map, zrow, out, n4);
    } else {
        int n4 = out_size / 4;
        pps_zero<<<(n4 + 255) / 256, 256, 0, stream>>>((float4*)out, n4);
        int total = P * PC;
        pps_scatter_feat<<<(total + 255) / 256, 256, 0, stream>>>(feat, coords, out, total);
    }
}